// Round 3
// baseline (154.749 us; speedup 1.0000x reference)
//
#include <hip/hip_runtime.h>

// Model: enc linear(37->64)+relu -> BiLSTM(H=64, T=128, B=2048) -> (degenerate
// attention == sum over T) -> 10-step decoder LSTM with constant input -> softmax(11).
//
// Exploits: attention weights are all-ones (softmax over a size-1 axis), so
// fd[b] = sum_t concat(hf,hb)[b,t,:] and att1/att2 are dead. fd@dec_wih.T is
// hoisted out of the decoder loop.
//
// R3: encoder fused INTO bilstm (4 enc waves, one per SIMD, compute e[t+1]
// tile per step into double-buffered LDS B-frag buffer; x prefetched 2 steps
// ahead). 1024 threads / 16 waves = 4 waves/SIMD; 1 cell/lane; recurrent MFMAs
// as two independent 2-chains. exp2-folded gates; lgkm-only step barrier.

typedef _Float16 f16;
typedef f16 f16x8 __attribute__((ext_vector_type(8)));
typedef f16 f16x4 __attribute__((ext_vector_type(4)));
typedef float f32x4 __attribute__((ext_vector_type(4)));

#define MFMA16(a, b, c) __builtin_amdgcn_mfma_f32_16x16x32_f16(a, b, c, 0, 0, 0)

// gate scales folded into weights: i,f,o -> -log2e ; g -> -2*log2e
// then sig = rcp(1+exp2(y)), tanh = 2*rcp(1+exp2(y)) - 1.
#define NLOG2E  -1.4426950408889634f
#define N2LOG2E -2.8853900817779268f

__device__ __forceinline__ float rcp_(float x) { return __builtin_amdgcn_rcpf(x); }
__device__ __forceinline__ float ex2_(float x) { return __builtin_amdgcn_exp2f(x); }
__device__ __forceinline__ float sigf(float x) { return 1.f / (1.f + __expf(-x)); }
__device__ __forceinline__ float tanhf_fast(float x) {
  float e = __expf(2.f * x);
  return 1.f - 2.f / (e + 1.f);
}

// B-frag LDS layout (per ksub half): [64 slots][8 f16]; slot = b | ((k>>3)&3)<<4,
// elem = k&7, ksub = k>>5. Lane l reads slot l as f16x8 -> B[k][b] for the
// 16x16x32 MFMA (b = l&15, k = 8*(l>>4)+i+32*ksub).

// ---------------- Kernel 1: fused encoder + BiLSTM + fd accumulation --------
__global__ __launch_bounds__(1024, 4) void bilstm_fused_k(
    const float* __restrict__ x, const float* __restrict__ w1,
    const float* __restrict__ b1,
    const float* __restrict__ wih_f, const float* __restrict__ whh_f,
    const float* __restrict__ bih_f, const float* __restrict__ bhh_f,
    const float* __restrict__ wih_b, const float* __restrict__ whh_b,
    const float* __restrict__ bih_b, const float* __restrict__ bhh_b,
    float* __restrict__ fd) {
  const int bid = blockIdx.x;
  const int dir = bid >> 7;
  const int bg = bid & 127;
  const int tid = threadIdx.x;
  const int w = tid >> 6, l = tid & 63;      // w in [0,16)
  const int rho = l & 15, c = l >> 4;
  const int gate = rho & 3, uoff = rho >> 2;

  const float* wih = dir ? wih_b : wih_f;
  const float* whh = dir ? whh_b : whh_f;
  const float* bih = dir ? bih_b : bih_f;
  const float* bhh = dir ? bhh_b : bhh_f;

  __shared__ __align__(16) f16 hbuf[2][2][64][8];  // 4 KB, double-buffered h
  __shared__ __align__(16) f16 ebuf[2][2][64][8];  // 4 KB, double-buffered e

  { int* hz = (int*)hbuf; hz[tid] = 0; }  // exactly 1024 ints

  // ---- recurrent weights: m-tile m = w, cell j = 4w + c, 1 cell/lane ----
  const float sA = (gate == 2) ? N2LOG2E : NLOG2E;
  const int n = gate * 64 + 4 * w + uoff;   // permuted gate-row -> W row
  f16x8 aih[2], ahh[2];
#pragma unroll
  for (int ks = 0; ks < 2; ks++) {
    const float* p1 = wih + n * 64 + ks * 32 + c * 8;
    const float* p2 = whh + n * 64 + ks * 32 + c * 8;
    f16x8 v1, v2;
#pragma unroll
    for (int i = 0; i < 8; i++) {
      v1[i] = (f16)(p1[i] * sA);
      v2[i] = (f16)(p2[i] * sA);
    }
    aih[ks] = v1;
    ahh[ks] = v2;
  }
  const int j = 4 * w + c;
  f32x4 bias0;
#pragma unroll
  for (int r = 0; r < 4; r++) {
    const float sr = (r == 2) ? N2LOG2E : NLOG2E;
    bias0[r] = (bih[64 * r + j] + bhh[64 * r + j]) * sr;
  }

  // ---- enc-wave setup (waves 0..3; one per SIMD) ----
  const bool enc = (w < 4);
  const int q = w;                           // e m-tile: units d = 16q..16q+15
  f16x8 w1a0 = {}, w1a1 = {};
  f32x4 eb = {};
  float xc[8], xc2[5], xn[8], xn2[5];
  const float* xrow = x + (size_t)(bg * 16 + rho) * 128 * 37;
  if (enc) {
#pragma unroll
    for (int i = 0; i < 8; i++) w1a0[i] = (f16)w1[(16 * q + rho) * 37 + 8 * c + i];
#pragma unroll
    for (int i = 0; i < 8; i++) {
      const int k = 32 + 8 * c + i;
      w1a1[i] = (f16)((c == 0 && k < 37) ? w1[(16 * q + rho) * 37 + k] : 0.f);
    }
#pragma unroll
    for (int r = 0; r < 4; r++) eb[r] = b1[16 * q + 4 * c + r];

    // x for logical step 0 -> e[0] now; step 1 into xc; step 2 into xn.
    {
      const float* p = xrow + (dir ? 127 : 0) * 37;
      float xt[8], xt2[5];
#pragma unroll
      for (int i = 0; i < 8; i++) xt[i] = p[8 * c + i];
#pragma unroll
      for (int i = 0; i < 5; i++) xt2[i] = (c == 0) ? p[32 + i] : 0.f;
      f16x8 xb0, xb1;
#pragma unroll
      for (int i = 0; i < 8; i++) xb0[i] = (f16)xt[i];
#pragma unroll
      for (int i = 0; i < 8; i++) xb1[i] = (f16)(i < 5 ? xt2[i] : 0.f);
      f32x4 ea = MFMA16(w1a0, xb0, eb);
      ea = MFMA16(w1a1, xb1, ea);
      f16x4 pk;
#pragma unroll
      for (int r = 0; r < 4; r++) pk[r] = (f16)fmaxf(ea[r], 0.f);
      const int d0 = 16 * q + 4 * c;
      *(f16x4*)&ebuf[0][q >> 1][rho | (((d0 >> 3) & 3) << 4)][d0 & 7] = pk;
    }
    {
      const float* p = xrow + (dir ? 126 : 1) * 37;
#pragma unroll
      for (int i = 0; i < 8; i++) xc[i] = p[8 * c + i];
#pragma unroll
      for (int i = 0; i < 5; i++) xc2[i] = (c == 0) ? p[32 + i] : 0.f;
    }
    {
      const float* p = xrow + (dir ? 125 : 2) * 37;
#pragma unroll
      for (int i = 0; i < 8; i++) xn[i] = p[8 * c + i];
#pragma unroll
      for (int i = 0; i < 5; i++) xn2[i] = (c == 0) ? p[32 + i] : 0.f;
    }
  }

  float cst = 0.f, hs = 0.f;
  const f32x4 z4 = {0.f, 0.f, 0.f, 0.f};

  __syncthreads();  // hbuf zeros + ebuf[0] visible

  for (int t = 0; t < 128; t++) {
    const int cur = t & 1, nxt = cur ^ 1;
    // current-step fragments
    f16x8 e0 = *(const f16x8*)&ebuf[cur][0][l][0];
    f16x8 e1 = *(const f16x8*)&ebuf[cur][1][l][0];
    f16x8 h0 = *(const f16x8*)&hbuf[cur][0][l][0];
    f16x8 h1 = *(const f16x8*)&hbuf[cur][1][l][0];
    // two independent 2-deep MFMA chains
    f32x4 a1 = MFMA16(aih[0], e0, bias0);
    f32x4 a2 = MFMA16(aih[1], e1, z4);
    a1 = MFMA16(ahh[0], h0, a1);
    a2 = MFMA16(ahh[1], h1, a2);

    // enc waves: build e[t+1] into ebuf[nxt]; prefetch x two steps ahead
    if (enc && t + 1 < 128) {
      f16x8 xb0, xb1;
#pragma unroll
      for (int i = 0; i < 8; i++) xb0[i] = (f16)xc[i];
#pragma unroll
      for (int i = 0; i < 8; i++) xb1[i] = (f16)(i < 5 ? xc2[i] : 0.f);
      f32x4 ea = MFMA16(w1a0, xb0, eb);
      ea = MFMA16(w1a1, xb1, ea);
      f16x4 pk;
#pragma unroll
      for (int r = 0; r < 4; r++) pk[r] = (f16)fmaxf(ea[r], 0.f);
      const int d0 = 16 * q + 4 * c;
      *(f16x4*)&ebuf[nxt][q >> 1][rho | (((d0 >> 3) & 3) << 4)][d0 & 7] = pk;
      // shift pipeline and issue loads for step t+3 (clamped; unused if OOB)
#pragma unroll
      for (int i = 0; i < 8; i++) xc[i] = xn[i];
#pragma unroll
      for (int i = 0; i < 5; i++) xc2[i] = xn2[i];
      const int s3 = (t + 3 < 128) ? t + 3 : 127;
      const float* p = xrow + (dir ? 127 - s3 : s3) * 37;
#pragma unroll
      for (int i = 0; i < 8; i++) xn[i] = p[8 * c + i];
#pragma unroll
      for (int i = 0; i < 5; i++) xn2[i] = (c == 0) ? p[32 + i] : 0.f;
    }

    // pointwise LSTM cell (gates pre-scaled by -log2e / -2log2e)
    const f32x4 a = a1 + a2;
    const float ig = rcp_(1.f + ex2_(a[0]));
    const float fg = rcp_(1.f + ex2_(a[1]));
    const float gg = 2.f * rcp_(1.f + ex2_(a[2])) - 1.f;
    const float og = rcp_(1.f + ex2_(a[3]));
    cst = fg * cst + ig * gg;
    const float th = 2.f * rcp_(1.f + ex2_(cst * N2LOG2E)) - 1.f;
    const float h = og * th;
    hs += h;  // fd accumulation (sum over t; reversal irrelevant)
    hbuf[nxt][j >> 5][rho | (((j >> 3) & 3) << 4)][j & 7] = (f16)h;

    // lgkm-only barrier: LDS h/e exchange must drain; global x prefetch
    // (vmcnt) stays in flight across the step boundary.
    asm volatile("s_waitcnt lgkmcnt(0)\n\ts_barrier" ::: "memory");
  }

  fd[(size_t)(bg * 16 + rho) * 128 + dir * 64 + j] = hs;
}

// ---------------- Kernel 2: decoder (10 steps, constant input fd) -----------
__global__ __launch_bounds__(256) void decoder_k(
    const float* __restrict__ fd,
    const float* __restrict__ dwih, const float* __restrict__ dwhh,
    const float* __restrict__ dbih, const float* __restrict__ dbhh,
    const float* __restrict__ dlw, const float* __restrict__ dlb,
    const int* __restrict__ outlen_p, float* __restrict__ out) {
  const int b0 = blockIdx.x * 16;
  const int tid = threadIdx.x;
  const int w = tid >> 6, l = tid & 63;
  const int rho = l & 15, c = l >> 4;
  const int gate = rho & 3, uoff = rho >> 2;
  const int outlen = *outlen_p;

  __shared__ __align__(16) f16 hbuf[2][2][64][8];
  __shared__ float h32[64][16];
  __shared__ float ldslw[11 * 64];
  __shared__ float ldslb[16];
  __shared__ float lg[16][16];

  {
    int* hz = (int*)hbuf;
    for (int i = tid; i < (int)(sizeof(hbuf) / 4); i += 256) hz[i] = 0;
  }
  for (int i = tid; i < 704; i += 256) ldslw[i] = dlw[i];
  if (tid < 16) ldslb[tid] = (tid < 11) ? dlb[tid] : 0.f;

  f16x8 awhh[4][2];
  f32x4 acc0[4];  // bias + fd @ dec_wih^T : constant across steps
  {
    f16x8 bfd[4];
#pragma unroll
    for (int ks = 0; ks < 4; ks++) {
      const float* p = fd + (size_t)(b0 + rho) * 128 + ks * 32 + c * 8;
      f16x8 v;
#pragma unroll
      for (int i = 0; i < 8; i++) v[i] = (f16)p[i];
      bfd[ks] = v;
    }
#pragma unroll
    for (int q = 0; q < 4; q++) {
      const int m = 4 * w + q;
      const int n = gate * 64 + 4 * m + uoff;
      f32x4 a;
      const int j = 16 * w + 4 * q + c;
#pragma unroll
      for (int r = 0; r < 4; r++) a[r] = dbih[64 * r + j] + dbhh[64 * r + j];
#pragma unroll
      for (int ks = 0; ks < 4; ks++) {
        const float* p = dwih + n * 128 + ks * 32 + c * 8;
        f16x8 v;
#pragma unroll
        for (int i = 0; i < 8; i++) v[i] = (f16)p[i];
        a = MFMA16(v, bfd[ks], a);
      }
      acc0[q] = a;
#pragma unroll
      for (int ks = 0; ks < 2; ks++) {
        const float* p = dwhh + n * 64 + ks * 32 + c * 8;
        f16x8 v;
#pragma unroll
        for (int i = 0; i < 8; i++) v[i] = (f16)p[i];
        awhh[q][ks] = v;
      }
    }
  }
  float cst[4] = {0.f, 0.f, 0.f, 0.f};
  __syncthreads();

  for (int s = 0; s < outlen; s++) {
    const int cur = s & 1;
    f16x8 h0 = *(const f16x8*)&hbuf[cur][0][l][0];
    f16x8 h1 = *(const f16x8*)&hbuf[cur][1][l][0];
#pragma unroll
    for (int q = 0; q < 4; q++) {
      f32x4 a = acc0[q];
      a = MFMA16(awhh[q][0], h0, a);
      a = MFMA16(awhh[q][1], h1, a);
      const float ig = sigf(a[0]);
      const float fg = sigf(a[1]);
      const float gg = tanhf_fast(a[2]);
      const float og = sigf(a[3]);
      cst[q] = fg * cst[q] + ig * gg;
      const float h = og * tanhf_fast(cst[q]);
      const int j = 16 * w + 4 * q + c;
      hbuf[cur ^ 1][j >> 5][rho | (((j >> 3) & 3) << 4)][j & 7] = (f16)h;
      h32[j][rho] = h;
    }
    __syncthreads();
    const int b = tid >> 4, o = tid & 15;
    float logit = 0.f;
    if (o < 11) {
      logit = ldslb[o];
      for (int jj = 0; jj < 64; jj++) logit += h32[jj][b] * ldslw[o * 64 + jj];
      lg[b][o] = logit;
    }
    __syncthreads();
    if (o < 11) {
      float mx = lg[b][0];
      for (int k = 1; k < 11; k++) mx = fmaxf(mx, lg[b][k]);
      float sum = 0.f;
      for (int k = 0; k < 11; k++) sum += __expf(lg[b][k] - mx);
      out[(size_t)(b0 + b) * outlen * 11 + (size_t)s * 11 + o] =
          __expf(logit - mx) / sum;
    }
    __syncthreads();
  }
}

extern "C" void kernel_launch(void* const* d_in, const int* in_sizes, int n_in,
                              void* d_out, int out_size, void* d_ws, size_t ws_size,
                              hipStream_t stream) {
  const float* x = (const float*)d_in[0];
  const float* w1 = (const float*)d_in[1];
  const float* b1 = (const float*)d_in[2];
  const float* wih_f = (const float*)d_in[3];
  const float* whh_f = (const float*)d_in[4];
  const float* bih_f = (const float*)d_in[5];
  const float* bhh_f = (const float*)d_in[6];
  const float* wih_b = (const float*)d_in[7];
  const float* whh_b = (const float*)d_in[8];
  const float* bih_b = (const float*)d_in[9];
  const float* bhh_b = (const float*)d_in[10];
  // d_in[11..14]: attention weights — provably dead (softmax over size-1 axis)
  const float* dwih = (const float*)d_in[15];
  const float* dwhh = (const float*)d_in[16];
  const float* dbih = (const float*)d_in[17];
  const float* dbhh = (const float*)d_in[18];
  const float* dlw = (const float*)d_in[19];
  const float* dlb = (const float*)d_in[20];
  const int* outlen = (const int*)d_in[21];
  float* out = (float*)d_out;

  float* fd = (float*)d_ws;  // 1 MB

  hipLaunchKernelGGL(bilstm_fused_k, dim3(256), dim3(1024), 0, stream,
                     x, w1, b1, wih_f, whh_f, bih_f, bhh_f,
                     wih_b, whh_b, bih_b, bhh_b, fd);
  hipLaunchKernelGGL(decoder_k, dim3(128), dim3(256), 0, stream,
                     fd, dwih, dwhh, dbih, dbhh, dlw, dlb, outlen, out);
}

// Round 4
// 136.581 us; speedup vs baseline: 1.1330x; 1.1330x over previous
//
#include <hip/hip_runtime.h>

// Model: enc linear(37->64)+relu -> BiLSTM(H=64, T=128, B=2048) -> (degenerate
// attention == sum over T) -> 10-step decoder LSTM with constant input -> softmax(11).
//
// Exploits: attention weights are all-ones (softmax over a size-1 axis), so
// fd[b] = sum_t concat(hf,hb)[b,t,:] and att1/att2 are dead. fd@dec_wih.T is
// hoisted out of the decoder loop.
//
// R4: enc_linear rewritten with coalesced LDS staging (the R2 version's
// stride-18.9KB 148B-segment x gather was ~50us); bilstm is the proven R2
// 8-wave kernel + e-prefetch distance 3 + unroll 4. R3's enc-fusion reverted
// (uncoalesced x gather on the barrier-locked critical loop: 143us).

typedef _Float16 f16;
typedef f16 f16x8 __attribute__((ext_vector_type(8)));
typedef f16 f16x4 __attribute__((ext_vector_type(4)));
typedef float f32x4 __attribute__((ext_vector_type(4)));

#define MFMA16(a, b, c) __builtin_amdgcn_mfma_f32_16x16x32_f16(a, b, c, 0, 0, 0)

// gate scales folded into weights: i,f,o -> -log2e ; g -> -2*log2e
// then sig = rcp(1+exp2(y)), tanh = 2*rcp(1+exp2(y)) - 1.
#define NLOG2E  -1.4426950408889634f
#define N2LOG2E -2.8853900817779268f

__device__ __forceinline__ float rcp_(float x) { return __builtin_amdgcn_rcpf(x); }
__device__ __forceinline__ float ex2_(float x) { return __builtin_amdgcn_exp2f(x); }
__device__ __forceinline__ float sigf(float x) { return 1.f / (1.f + __expf(-x)); }
__device__ __forceinline__ float tanhf_fast(float x) {
  float e = __expf(2.f * x);
  return 1.f - 2.f / (e + 1.f);
}

// e-fragment tensor layout (f16, 32 MB in d_ws):
//   addr16B = ((t*128 + bgroup)*2 + ksub)*64 + slot ; slot = (b&15) | (((k>>3)&3)<<4)
//   within-slot element i = k&7 ; k = ksub*32 + 8*(slot>>4) + i
// == the 16x16x32 MFMA B-fragment for B[k][b] = e[b][k].

// ---------------- Kernel A: e = relu(x @ W1^T + b1), coalesced staging ------
// Block: 16 batch rows (bg) x 8 timesteps (tc). A = W1 (rows=units, K=37 pad
// 64), B = x^T (cols=batch). C/D: row=unit d, col=batch b -> f16x4 per lane
// lands contiguously in the fragment slot.
#define TC 8
__global__ __launch_bounds__(256) void enc_linear_k(
    const float* __restrict__ x, const float* __restrict__ w1,
    const float* __restrict__ b1, f16* __restrict__ efrag) {
  const int bg = blockIdx.x;   // 0..127
  const int tc = blockIdx.y;   // 0..15
  const int tid = threadIdx.x;
  const int w = tid >> 6, l = tid & 63;
  const int rho = l & 15, c = l >> 4;

  __shared__ float xls[16][8 * 37 + 1];                 // +1 pad: 9-mod-32 stride
  __shared__ float ldsw[64 * 37];
  __shared__ __align__(16) f16 fstage[TC][2][64][8];

  for (int i = tid; i < 64 * 37; i += 256) ldsw[i] = w1[i];
  // coalesced x stage: wave w copies rows 4w..4w+3, each a contiguous 1184B x2
#pragma unroll
  for (int rr = 0; rr < 4; rr++) {
    const int r = w * 4 + rr;
    const float* src = x + ((size_t)(bg * 16 + r) * 128 + tc * TC) * 37;
    for (int e = l; e < 296; e += 64) xls[r][e] = src[e];
  }
  __syncthreads();

  // A-frag: W1 rows 16w+rho, k = 8c+i (ks0), 32+i c==0 (ks1; 37 pad to 64)
  f16x8 a0, a1;
  {
    const float* pw = ldsw + (16 * w + rho) * 37;
#pragma unroll
    for (int i = 0; i < 8; i++) a0[i] = (f16)pw[8 * c + i];
#pragma unroll
    for (int i = 0; i < 8; i++) a1[i] = (f16)((c == 0 && i < 5) ? pw[32 + i] : 0.f);
  }
  f32x4 bias;
#pragma unroll
  for (int r = 0; r < 4; r++) bias[r] = b1[16 * w + 4 * c + r];

#pragma unroll
  for (int tl = 0; tl < TC; tl++) {
    // B-frag: b = rho, k = 8c+i -> xls[rho][tl*37 + k]
    const float* px = &xls[rho][tl * 37];
    f16x8 xb0, xb1;
#pragma unroll
    for (int i = 0; i < 8; i++) xb0[i] = (f16)px[8 * c + i];
#pragma unroll
    for (int i = 0; i < 8; i++) xb1[i] = (f16)((c == 0 && i < 5) ? px[32 + i] : 0.f);
    f32x4 acc = bias;
    acc = MFMA16(a0, xb0, acc);
    acc = MFMA16(a1, xb1, acc);
    // d = 16w + 4c + r ; ksub = w>>1 ; slot = rho | (((d0>>3)&3)<<4) ; elems d0&7..+3
    f16x4 pk;
#pragma unroll
    for (int r = 0; r < 4; r++) pk[r] = (f16)fmaxf(acc[r], 0.f);
    const int d0 = 16 * w + 4 * c;
    *(f16x4*)&fstage[tl][w >> 1][rho | (((d0 >> 3) & 3) << 4)][d0 & 7] = pk;
  }
  __syncthreads();

  // bulk store: TC*2*64 float4s, fully coalesced
  const float4* srcf = (const float4*)fstage;
  float4* dstf = (float4*)efrag;
  for (int i = tid; i < TC * 2 * 64; i += 256) {
    const int tl = i >> 7, rest = i & 127;
    dstf[((size_t)((tc * TC + tl) * 128 + bg) * 2) * 64 + rest] = srcf[i];
  }
}

// ---------------- Kernel B: BiLSTM, fd accumulation ----------------
// 8 waves/block (512 thr): wave w owns m-tiles {2w, 2w+1}; gate-interleaved row
// permutation puts all 4 gates of cell (b, j) into one lane's 4 acc regs.
__global__ __launch_bounds__(512, 2) void bilstm_k(
    const f16* __restrict__ efrag,
    const float* __restrict__ wih_f, const float* __restrict__ whh_f,
    const float* __restrict__ bih_f, const float* __restrict__ bhh_f,
    const float* __restrict__ wih_b, const float* __restrict__ whh_b,
    const float* __restrict__ bih_b, const float* __restrict__ bhh_b,
    float* __restrict__ fd) {
  const int bid = blockIdx.x;
  const int dir = bid >> 7;
  const int bg = bid & 127;
  const int tid = threadIdx.x;
  const int w = tid >> 6, l = tid & 63;      // w in [0,8)
  const int rho = l & 15, c = l >> 4;
  const int gate = rho & 3, uoff = rho >> 2;

  const float* wih = dir ? wih_b : wih_f;
  const float* whh = dir ? whh_b : whh_f;
  const float* bih = dir ? bih_b : bih_f;
  const float* bhh = dir ? bhh_b : bhh_f;

  __shared__ __align__(16) f16 hbuf[2][2][64][8];
  {
    int* hz = (int*)hbuf;
    for (int i = tid; i < (int)(sizeof(hbuf) / 4); i += 512) hz[i] = 0;
  }

  // Row scale by gate (exp2 folding): rows of gate g scaled by SG[g].
  const float sA = (gate == 2) ? N2LOG2E : NLOG2E;

  // Permuted-weight A-fragments, registers for all 128 steps.
  // m-tile m = 2w+q; fragment row rho -> original W row n = 64*gate + 4m + uoff.
  f16x8 aih[2][2], ahh[2][2];
#pragma unroll
  for (int q = 0; q < 2; q++) {
    const int m = 2 * w + q;
    const int n = gate * 64 + 4 * m + uoff;
#pragma unroll
    for (int ks = 0; ks < 2; ks++) {
      const float* p1 = wih + n * 64 + ks * 32 + c * 8;
      const float* p2 = whh + n * 64 + ks * 32 + c * 8;
      f16x8 v1, v2;
#pragma unroll
      for (int i = 0; i < 8; i++) {
        v1[i] = (f16)(p1[i] * sA);
        v2[i] = (f16)(p2[i] * sA);
      }
      aih[q][ks] = v1;
      ahh[q][ks] = v2;
    }
  }
  // Per-lane bias: acc reg r of m-tile q is gate r of unit j = 8w + 4q + c.
  f32x4 bias[2];
#pragma unroll
  for (int q = 0; q < 2; q++) {
    const int j = 8 * w + 4 * q + c;
#pragma unroll
    for (int r = 0; r < 4; r++) {
      const float sr = (r == 2) ? N2LOG2E : NLOG2E;
      bias[q][r] = (bih[64 * r + j] + bhh[64 * r + j]) * sr;
    }
  }

  const f16x8* eb = (const f16x8*)efrag;
#define EIDX(t) (((size_t)(((dir ? 127 - (t) : (t)) * 128) + bg) * 2) * 64 + l)
  // 3-deep e prefetch pipeline: ~1600cy of cover for L2/HBM misses.
  f16x8 ec0 = eb[EIDX(0)], ec1 = eb[EIDX(0) + 64];
  f16x8 e10 = eb[EIDX(1)], e11 = eb[EIDX(1) + 64];
  f16x8 e20 = eb[EIDX(2)], e21 = eb[EIDX(2) + 64];

  float cst[2] = {0.f, 0.f};
  float hs[2] = {0.f, 0.f};

  __syncthreads();  // hbuf zeros visible

#pragma unroll 4
  for (int t = 0; t < 128; t++) {
    const int cur = t & 1;
    // issue prefetch for t+3 (clamped; redundant loads at tail are harmless)
    const int t3 = (t + 3 < 128) ? t + 3 : 127;
    const f16x8 ld0 = eb[EIDX(t3)];
    const f16x8 ld1 = eb[EIDX(t3) + 64];

    f16x8 h0 = *(const f16x8*)&hbuf[cur][0][l][0];
    f16x8 h1 = *(const f16x8*)&hbuf[cur][1][l][0];
#pragma unroll
    for (int q = 0; q < 2; q++) {
      f32x4 a = bias[q];
      a = MFMA16(aih[q][0], ec0, a);
      a = MFMA16(aih[q][1], ec1, a);
      a = MFMA16(ahh[q][0], h0, a);
      a = MFMA16(ahh[q][1], h1, a);
      // pointwise: sig = rcp(1+exp2(y)), tanh = 2*rcp(1+exp2(y)) - 1
      const float ig = rcp_(1.f + ex2_(a[0]));
      const float fg = rcp_(1.f + ex2_(a[1]));
      const float gg = 2.f * rcp_(1.f + ex2_(a[2])) - 1.f;
      const float og = rcp_(1.f + ex2_(a[3]));
      cst[q] = fg * cst[q] + ig * gg;
      const float th = 2.f * rcp_(1.f + ex2_(cst[q] * N2LOG2E)) - 1.f;
      const float h = og * th;
      hs[q] += h;  // fd accumulation (sum over t; reversal irrelevant)
      const int j = 8 * w + 4 * q + c;
      hbuf[cur ^ 1][j >> 5][rho | (((j >> 3) & 3) << 4)][j & 7] = (f16)h;
    }
    // rotate prefetch pipeline (unroll 4 renames these away)
    ec0 = e10; ec1 = e11;
    e10 = e20; e11 = e21;
    e20 = ld0; e21 = ld1;
    // lgkm-only barrier: LDS h exchange must drain; global e prefetch
    // (vmcnt) stays in flight across the step boundary.
    asm volatile("s_waitcnt lgkmcnt(0)\n\ts_barrier" ::: "memory");
  }
#undef EIDX
#pragma unroll
  for (int q = 0; q < 2; q++) {
    const int j = 8 * w + 4 * q + c;
    fd[(size_t)(bg * 16 + rho) * 128 + dir * 64 + j] = hs[q];
  }
}

// ---------------- Kernel C: decoder (10 steps, constant input fd) -----------
__global__ __launch_bounds__(256) void decoder_k(
    const float* __restrict__ fd,
    const float* __restrict__ dwih, const float* __restrict__ dwhh,
    const float* __restrict__ dbih, const float* __restrict__ dbhh,
    const float* __restrict__ dlw, const float* __restrict__ dlb,
    const int* __restrict__ outlen_p, float* __restrict__ out) {
  const int b0 = blockIdx.x * 16;
  const int tid = threadIdx.x;
  const int w = tid >> 6, l = tid & 63;
  const int rho = l & 15, c = l >> 4;
  const int gate = rho & 3, uoff = rho >> 2;
  const int outlen = *outlen_p;

  __shared__ __align__(16) f16 hbuf[2][2][64][8];
  __shared__ float h32[64][16];
  __shared__ float ldslw[11 * 64];
  __shared__ float ldslb[16];
  __shared__ float lg[16][16];

  {
    int* hz = (int*)hbuf;
    for (int i = tid; i < (int)(sizeof(hbuf) / 4); i += 256) hz[i] = 0;
  }
  for (int i = tid; i < 704; i += 256) ldslw[i] = dlw[i];
  if (tid < 16) ldslb[tid] = (tid < 11) ? dlb[tid] : 0.f;

  f16x8 awhh[4][2];
  f32x4 acc0[4];  // bias + fd @ dec_wih^T : constant across steps
  {
    f16x8 bfd[4];
#pragma unroll
    for (int ks = 0; ks < 4; ks++) {
      const float* p = fd + (size_t)(b0 + rho) * 128 + ks * 32 + c * 8;
      f16x8 v;
#pragma unroll
      for (int i = 0; i < 8; i++) v[i] = (f16)p[i];
      bfd[ks] = v;
    }
#pragma unroll
    for (int q = 0; q < 4; q++) {
      const int m = 4 * w + q;
      const int n = gate * 64 + 4 * m + uoff;
      f32x4 a;
      const int j = 16 * w + 4 * q + c;
#pragma unroll
      for (int r = 0; r < 4; r++) a[r] = dbih[64 * r + j] + dbhh[64 * r + j];
#pragma unroll
      for (int ks = 0; ks < 4; ks++) {
        const float* p = dwih + n * 128 + ks * 32 + c * 8;
        f16x8 v;
#pragma unroll
        for (int i = 0; i < 8; i++) v[i] = (f16)p[i];
        a = MFMA16(v, bfd[ks], a);
      }
      acc0[q] = a;
#pragma unroll
      for (int ks = 0; ks < 2; ks++) {
        const float* p = dwhh + n * 64 + ks * 32 + c * 8;
        f16x8 v;
#pragma unroll
        for (int i = 0; i < 8; i++) v[i] = (f16)p[i];
        awhh[q][ks] = v;
      }
    }
  }
  float cst[4] = {0.f, 0.f, 0.f, 0.f};
  __syncthreads();

  for (int s = 0; s < outlen; s++) {
    const int cur = s & 1;
    f16x8 h0 = *(const f16x8*)&hbuf[cur][0][l][0];
    f16x8 h1 = *(const f16x8*)&hbuf[cur][1][l][0];
#pragma unroll
    for (int q = 0; q < 4; q++) {
      f32x4 a = acc0[q];
      a = MFMA16(awhh[q][0], h0, a);
      a = MFMA16(awhh[q][1], h1, a);
      const float ig = sigf(a[0]);
      const float fg = sigf(a[1]);
      const float gg = tanhf_fast(a[2]);
      const float og = sigf(a[3]);
      cst[q] = fg * cst[q] + ig * gg;
      const float h = og * tanhf_fast(cst[q]);
      const int j = 16 * w + 4 * q + c;
      hbuf[cur ^ 1][j >> 5][rho | (((j >> 3) & 3) << 4)][j & 7] = (f16)h;
      h32[j][rho] = h;
    }
    __syncthreads();
    const int b = tid >> 4, o = tid & 15;
    float logit = 0.f;
    if (o < 11) {
      logit = ldslb[o];
      for (int jj = 0; jj < 64; jj++) logit += h32[jj][b] * ldslw[o * 64 + jj];
      lg[b][o] = logit;
    }
    __syncthreads();
    if (o < 11) {
      float mx = lg[b][0];
      for (int k = 1; k < 11; k++) mx = fmaxf(mx, lg[b][k]);
      float sum = 0.f;
      for (int k = 0; k < 11; k++) sum += __expf(lg[b][k] - mx);
      out[(size_t)(b0 + b) * outlen * 11 + (size_t)s * 11 + o] =
          __expf(logit - mx) / sum;
    }
    __syncthreads();
  }
}

extern "C" void kernel_launch(void* const* d_in, const int* in_sizes, int n_in,
                              void* d_out, int out_size, void* d_ws, size_t ws_size,
                              hipStream_t stream) {
  const float* x = (const float*)d_in[0];
  const float* w1 = (const float*)d_in[1];
  const float* b1 = (const float*)d_in[2];
  const float* wih_f = (const float*)d_in[3];
  const float* whh_f = (const float*)d_in[4];
  const float* bih_f = (const float*)d_in[5];
  const float* bhh_f = (const float*)d_in[6];
  const float* wih_b = (const float*)d_in[7];
  const float* whh_b = (const float*)d_in[8];
  const float* bih_b = (const float*)d_in[9];
  const float* bhh_b = (const float*)d_in[10];
  // d_in[11..14]: attention weights — provably dead (softmax over size-1 axis)
  const float* dwih = (const float*)d_in[15];
  const float* dwhh = (const float*)d_in[16];
  const float* dbih = (const float*)d_in[17];
  const float* dbhh = (const float*)d_in[18];
  const float* dlw = (const float*)d_in[19];
  const float* dlb = (const float*)d_in[20];
  const int* outlen = (const int*)d_in[21];
  float* out = (float*)d_out;

  f16* efrag = (f16*)d_ws;                              // 32 MB
  float* fd = (float*)((char*)d_ws + (size_t)33554432); // 1 MB

  hipLaunchKernelGGL(enc_linear_k, dim3(128, 16), dim3(256), 0, stream,
                     x, w1, b1, efrag);
  hipLaunchKernelGGL(bilstm_k, dim3(256), dim3(512), 0, stream,
                     efrag, wih_f, whh_f, bih_f, bhh_f,
                     wih_b, whh_b, bih_b, bhh_b, fd);
  hipLaunchKernelGGL(decoder_k, dim3(128), dim3(256), 0, stream,
                     fd, dwih, dwhh, dbih, dbhh, dlw, dlb, outlen, out);
}